// Round 2
// baseline (268.597 us; speedup 1.0000x reference)
//
#include <hip/hip_runtime.h>

// Batched 3D affine spatial transformer: vol [B=4,160,192,160,1] fp32, trf [4,4,4] fp32.
// One thread handles 4 consecutive-w voxels (W=160 divisible by 4, same row) to amortize
// div/mod + affine setup and to emit one float4 store.
constexpr int D = 160, H = 192, W = 160, B = 4;
constexpr int V = D * H * W;      // 4,915,200
constexpr int W4 = W / 4;         // 40
constexpr int NT = V / 4;         // 1,228,800 threads per batch = 4800 * 256 exactly

struct DimS { int i0, i1; float w0, w1; };

// Faithful to neuron.utils interpn clipping semantics:
//   clipped = clip(loc,0,max); l0 = clip(floor(loc),0,max); i1 = min(i0+1, maxi)
//   w0 (corner bit 0 -> l0) = l1 - clipped ; w1 (corner bit 1 -> l1) = 1 - w0
__device__ __forceinline__ DimS prep_dim(float loc, float maxv, int maxi) {
    float cl = fminf(fmaxf(loc, 0.0f), maxv);
    float l0 = fminf(fmaxf(floorf(loc), 0.0f), maxv);
    float l1 = fminf(l0 + 1.0f, maxv);
    DimS s;
    s.w0 = l1 - cl;
    s.w1 = 1.0f - s.w0;
    s.i0 = (int)l0;
    s.i1 = min(s.i0 + 1, maxi);   // == (int)l1
    return s;
}

__global__ __launch_bounds__(256) void st_affine_kernel(
        const float* __restrict__ vol, const float* __restrict__ trf,
        float* __restrict__ out) {
    const int b   = blockIdx.z;
    const int tid = blockIdx.x * 256 + threadIdx.x;   // exact grid, no tail

    // tid -> (d, h, w4); constants -> magic-multiply division
    const int w4 = tid % W4;
    const int t  = tid / W4;
    const int h  = t % H;
    const int d  = t / H;

    // Affine rows: wave-uniform per block -> scalar loads
    const float* __restrict__ A = trf + b * 16;
    const float a00 = A[0], a01 = A[1], a02 = A[2],  a03 = A[3];
    const float a10 = A[4], a11 = A[5], a12 = A[6],  a13 = A[7];
    const float a20 = A[8], a21 = A[9], a22 = A[10], a23 = A[11];

    constexpr float cd = (D - 1) * 0.5f;
    constexpr float ch = (H - 1) * 0.5f;
    constexpr float cw = (W - 1) * 0.5f;

    const float md = (float)d - cd;
    const float mh = (float)h - ch;
    const float mw0 = (float)(w4 * 4) - cw;

    // Hoist the (d,h)-dependent part of loc = center + A[:3,:3]@mesh_c + A[:3,3]
    const float bd = fmaf(a00, md, fmaf(a01, mh, a03));
    const float bh = fmaf(a10, md, fmaf(a11, mh, a13));
    const float bw = fmaf(a20, md, fmaf(a21, mh, a23));

    const float* __restrict__ vb = vol + (size_t)b * V;

    float res[4];
    #pragma unroll
    for (int j = 0; j < 4; ++j) {
        const float mw = mw0 + (float)j;
        const float ld = cd + fmaf(a02, mw, bd);
        const float lh = ch + fmaf(a12, mw, bh);
        const float lw = cw + fmaf(a22, mw, bw);

        const DimS sd = prep_dim(ld, (float)(D - 1), D - 1);
        const DimS sh = prep_dim(lh, (float)(H - 1), H - 1);
        const DimS sw = prep_dim(lw, (float)(W - 1), W - 1);

        const int r00 = (sd.i0 * H + sh.i0) * W;
        const int r01 = (sd.i0 * H + sh.i1) * W;
        const int r10 = (sd.i1 * H + sh.i0) * W;
        const int r11 = (sd.i1 * H + sh.i1) * W;

        const float v000 = vb[r00 + sw.i0];
        const float v001 = vb[r00 + sw.i1];
        const float v010 = vb[r01 + sw.i0];
        const float v011 = vb[r01 + sw.i1];
        const float v100 = vb[r10 + sw.i0];
        const float v101 = vb[r10 + sw.i1];
        const float v110 = vb[r11 + sw.i0];
        const float v111 = vb[r11 + sw.i1];

        const float pd0 = fmaf(sw.w0, v000, sw.w1 * v001);
        const float pd1 = fmaf(sw.w0, v010, sw.w1 * v011);
        const float pd2 = fmaf(sw.w0, v100, sw.w1 * v101);
        const float pd3 = fmaf(sw.w0, v110, sw.w1 * v111);

        const float q0 = fmaf(sh.w0, pd0, sh.w1 * pd1);
        const float q1 = fmaf(sh.w0, pd2, sh.w1 * pd3);

        res[j] = fmaf(sd.w0, q0, sd.w1 * q1);
    }

    float4 o = make_float4(res[0], res[1], res[2], res[3]);
    *reinterpret_cast<float4*>(out + (size_t)b * V + (size_t)tid * 4) = o;
}

extern "C" void kernel_launch(void* const* d_in, const int* in_sizes, int n_in,
                              void* d_out, int out_size, void* d_ws, size_t ws_size,
                              hipStream_t stream) {
    const float* vol = (const float*)d_in[0];
    const float* trf = (const float*)d_in[1];
    float* out = (float*)d_out;

    dim3 grid(NT / 256, 1, B);
    dim3 block(256, 1, 1);
    st_affine_kernel<<<grid, block, 0, stream>>>(vol, trf, out);
}

// Round 3
// 178.496 us; speedup vs baseline: 1.5048x; 1.5048x over previous
//
#include <hip/hip_runtime.h>

// Batched 3D affine spatial transformer: vol [B=4,160,192,160,1] fp32, trf [4,4,4] fp32.
// R3: 1 voxel/thread (lane-contiguous w — R2 showed widening lane stride wrecks FETCH),
// clip reformulated so i1==i0+1 always -> 4x paired dwordx2 gathers with constant
// offsets instead of 8x scattered dword; 3D grid kills the magic div/mod.
constexpr int D = 160, H = 192, W = 160, B = 4;
constexpr int V  = D * H * W;
constexpr int HW = H * W;

struct DimS { int i0; float w0; };

// Equivalent to neuron.utils interpn clipping:
//   c = clip(loc,0,max); i0 = min((int)c, max-1); i1 = i0+1 (always in-bounds);
//   w0 = (i0+1) - c ; w1 = 1 - w0.
// Case check vs reference: interior -> identical; loc<0 -> c=0,i0=0,w0=1 (all weight on
// v[0], same); loc>=max -> c=max,i0=max-1,w0=0 (all weight on v[max], same).
__device__ __forceinline__ DimS prep(float loc, float maxv, int maxi) {
    float c  = fminf(fmaxf(loc, 0.0f), maxv);
    int  i0  = min((int)c, maxi - 1);
    DimS s;
    s.i0 = i0;
    s.w0 = (float)(i0 + 1) - c;
    return s;
}

__global__ __launch_bounds__(256) void st_affine_kernel(
        const float* __restrict__ vol, const float* __restrict__ trf,
        float* __restrict__ out) {
    const int b = blockIdx.z;
    const int d = blockIdx.y;
    // grid.x = (H/8)*(W/32) = 24*5 = 120 ; block = (32,8)
    const int hblk = blockIdx.x / 5;          // scalar magic-div
    const int wblk = blockIdx.x - hblk * 5;   // scalar
    const int w = wblk * 32 + threadIdx.x;
    const int h = hblk * 8  + threadIdx.y;

    // Affine rows: b uniform per block -> scalar loads
    const float* __restrict__ A = trf + b * 16;
    const float a00 = A[0], a01 = A[1], a02 = A[2],  a03 = A[3];
    const float a10 = A[4], a11 = A[5], a12 = A[6],  a13 = A[7];
    const float a20 = A[8], a21 = A[9], a22 = A[10], a23 = A[11];

    constexpr float cd = (D - 1) * 0.5f;
    constexpr float ch = (H - 1) * 0.5f;
    constexpr float cw = (W - 1) * 0.5f;

    const float md = (float)d - cd;
    const float mh = (float)h - ch;
    const float mw = (float)w - cw;

    // loc = center + A[:3,:3] @ mesh_c + A[:3,3]
    const float ld = cd + fmaf(a00, md, fmaf(a01, mh, fmaf(a02, mw, a03)));
    const float lh = ch + fmaf(a10, md, fmaf(a11, mh, fmaf(a12, mw, a13)));
    const float lw = cw + fmaf(a20, md, fmaf(a21, mh, fmaf(a22, mw, a23)));

    const DimS sd = prep(ld, (float)(D - 1), D - 1);
    const DimS sh = prep(lh, (float)(H - 1), H - 1);
    const DimS sw = prep(lw, (float)(W - 1), W - 1);

    const float* __restrict__ vb = vol + (size_t)b * V;
    const float* p0 = vb + ((sd.i0 * H + sh.i0) * W + sw.i0);

    // 4 paired loads: (w,w+1) at the 4 (d,h) corners. Offsets are compile-time
    // constants: +W fits the 13-bit imm; +HW is one extra 64-bit add.
    float2 v00, v01, v10, v11;
    __builtin_memcpy(&v00, p0,          8);   // (d0,h0)
    __builtin_memcpy(&v01, p0 + W,      8);   // (d0,h1)
    __builtin_memcpy(&v10, p0 + HW,     8);   // (d1,h0)
    __builtin_memcpy(&v11, p0 + HW + W, 8);   // (d1,h1)

    // lerp form: w0*x + (1-w0)*y == y + w0*(x-y)
    const float pd00 = fmaf(sw.w0, v00.x - v00.y, v00.y);
    const float pd01 = fmaf(sw.w0, v01.x - v01.y, v01.y);
    const float pd10 = fmaf(sw.w0, v10.x - v10.y, v10.y);
    const float pd11 = fmaf(sw.w0, v11.x - v11.y, v11.y);

    const float q0 = fmaf(sh.w0, pd00 - pd01, pd01);
    const float q1 = fmaf(sh.w0, pd10 - pd11, pd11);
    const float r  = fmaf(sd.w0, q0 - q1, q1);

    out[(size_t)b * V + (size_t)(d * H + h) * W + w] = r;
}

extern "C" void kernel_launch(void* const* d_in, const int* in_sizes, int n_in,
                              void* d_out, int out_size, void* d_ws, size_t ws_size,
                              hipStream_t stream) {
    const float* vol = (const float*)d_in[0];
    const float* trf = (const float*)d_in[1];
    float* out = (float*)d_out;

    dim3 grid((H / 8) * (W / 32), D, B);   // (120, 160, 4)
    dim3 block(32, 8, 1);
    st_affine_kernel<<<grid, block, 0, stream>>>(vol, trf, out);
}

// Round 4
// 171.785 us; speedup vs baseline: 1.5636x; 1.0391x over previous
//
#include <hip/hip_runtime.h>

// Batched 3D affine spatial transformer: vol [B=4,160,192,160,1] fp32, trf [4,4,4] fp32.
// R4: 2 voxels/thread along d (lane stride in w stays 1 -> gather locality preserved,
// the R2 lesson), doubling loads-in-flight per wave (4 -> 8) to attack latency-bound
// profile (R3: no pipe >50%). Nontemporal stores keep streaming writes out of L2.
constexpr int D = 160, H = 192, W = 160, B = 4;
constexpr int V  = D * H * W;
constexpr int HW = H * W;

struct DimS { int i0; float w0; };

// Equivalent to neuron.utils interpn clipping:
//   c = clip(loc,0,max); i0 = min((int)c, max-1); i1 = i0+1 (always in-bounds);
//   w0 = (i0+1) - c. Interior/low-clip/high-clip all match reference (verified R3).
__device__ __forceinline__ DimS prep(float loc, float maxv, int maxi) {
    float c  = fminf(fmaxf(loc, 0.0f), maxv);
    int  i0  = min((int)c, maxi - 1);
    DimS s;
    s.i0 = i0;
    s.w0 = (float)(i0 + 1) - c;
    return s;
}

__device__ __forceinline__ float trilerp(const float* __restrict__ vb,
                                         DimS sd, DimS sh, DimS sw) {
    const float* p0 = vb + ((sd.i0 * H + sh.i0) * W + sw.i0);
    float2 v00, v01, v10, v11;
    __builtin_memcpy(&v00, p0,          8);
    __builtin_memcpy(&v01, p0 + W,      8);
    __builtin_memcpy(&v10, p0 + HW,     8);
    __builtin_memcpy(&v11, p0 + HW + W, 8);
    const float pd00 = fmaf(sw.w0, v00.x - v00.y, v00.y);
    const float pd01 = fmaf(sw.w0, v01.x - v01.y, v01.y);
    const float pd10 = fmaf(sw.w0, v10.x - v10.y, v10.y);
    const float pd11 = fmaf(sw.w0, v11.x - v11.y, v11.y);
    const float q0 = fmaf(sh.w0, pd00 - pd01, pd01);
    const float q1 = fmaf(sh.w0, pd10 - pd11, pd11);
    return fmaf(sd.w0, q0 - q1, q1);
}

__global__ __launch_bounds__(256) void st_affine_kernel(
        const float* __restrict__ vol, const float* __restrict__ trf,
        float* __restrict__ out) {
    const int b  = blockIdx.z;
    const int d0 = blockIdx.y * 2;            // this thread does d0 and d0+1
    // grid.x = (H/8)*(W/32) = 24*5 = 120 ; block = (32,8)
    const int hblk = blockIdx.x / 5;
    const int wblk = blockIdx.x - hblk * 5;
    const int w = wblk * 32 + threadIdx.x;
    const int h = hblk * 8  + threadIdx.y;

    const float* __restrict__ A = trf + b * 16;   // wave-uniform -> scalar loads
    const float a00 = A[0], a01 = A[1], a02 = A[2],  a03 = A[3];
    const float a10 = A[4], a11 = A[5], a12 = A[6],  a13 = A[7];
    const float a20 = A[8], a21 = A[9], a22 = A[10], a23 = A[11];

    constexpr float cd = (D - 1) * 0.5f;
    constexpr float ch = (H - 1) * 0.5f;
    constexpr float cw = (W - 1) * 0.5f;

    const float md = (float)d0 - cd;
    const float mh = (float)h  - ch;
    const float mw = (float)w  - cw;

    // Voxel 0: full affine; voxel 1 (d0+1): loc += column 0 of A.
    const float ld0 = cd + fmaf(a00, md, fmaf(a01, mh, fmaf(a02, mw, a03)));
    const float lh0 = ch + fmaf(a10, md, fmaf(a11, mh, fmaf(a12, mw, a13)));
    const float lw0 = cw + fmaf(a20, md, fmaf(a21, mh, fmaf(a22, mw, a23)));
    const float ld1 = ld0 + a00;
    const float lh1 = lh0 + a10;
    const float lw1 = lw0 + a20;

    const DimS sd0 = prep(ld0, (float)(D - 1), D - 1);
    const DimS sh0 = prep(lh0, (float)(H - 1), H - 1);
    const DimS sw0 = prep(lw0, (float)(W - 1), W - 1);
    const DimS sd1 = prep(ld1, (float)(D - 1), D - 1);
    const DimS sh1 = prep(lh1, (float)(H - 1), H - 1);
    const DimS sw1 = prep(lw1, (float)(W - 1), W - 1);

    const float* __restrict__ vb = vol + (size_t)b * V;

    const float r0 = trilerp(vb, sd0, sh0, sw0);
    const float r1 = trilerp(vb, sd1, sh1, sw1);

    float* ob = out + (size_t)b * V + (size_t)h * W + w;
    __builtin_nontemporal_store(r0, ob + (size_t)d0 * HW);
    __builtin_nontemporal_store(r1, ob + (size_t)(d0 + 1) * HW);
}

extern "C" void kernel_launch(void* const* d_in, const int* in_sizes, int n_in,
                              void* d_out, int out_size, void* d_ws, size_t ws_size,
                              hipStream_t stream) {
    const float* vol = (const float*)d_in[0];
    const float* trf = (const float*)d_in[1];
    float* out = (float*)d_out;

    dim3 grid((H / 8) * (W / 32), D / 2, B);   // (120, 80, 4)
    dim3 block(32, 8, 1);
    st_affine_kernel<<<grid, block, 0, stream>>>(vol, trf, out);
}